// Round 16
// baseline (147.266 us; speedup 1.0000x reference)
//
#include <hip/hip_runtime.h>

#define CCH   256
#define NSEQ  4096
#define NH    8
#define HD    32

typedef short s8x __attribute__((ext_vector_type(8)));
typedef float f4x __attribute__((ext_vector_type(4)));

__device__ __forceinline__ f4x mfma16(s8x a, s8x b, f4x c) {
  return __builtin_amdgcn_mfma_f32_16x16x32_bf16(a, b, c, 0, 0, 0);
}

__device__ __forceinline__ unsigned short f2bf(float f) {
  union { float f; unsigned int u; } v; v.f = f;
  unsigned int u = v.u + 0x7fffu + ((v.u >> 16) & 1u);
  return (unsigned short)(u >> 16);
}

__device__ __forceinline__ unsigned int pk_bf_rnd(float lo, float hi) {
  return (unsigned int)f2bf(lo) | ((unsigned int)f2bf(hi) << 16);
}

// pack two f32 -> one u32 of bf16 (truncating; P >= 0 so safe)
__device__ __forceinline__ unsigned int pk_bf_trunc(float lo, float hi) {
  union { float f; unsigned int u; } a, b; a.f = lo; b.f = hi;
  return __builtin_amdgcn_perm(b.u, a.u, 0x07060302);
}

// raw v_exp_f32
#if defined(__has_builtin)
#if __has_builtin(__builtin_amdgcn_exp2f)
#define FEXP2(x) __builtin_amdgcn_exp2f(x)
#endif
#endif
#ifndef FEXP2
__device__ __forceinline__ float __fexp2_asm(float x) {
  float r; asm("v_exp_f32 %0, %1" : "=v"(r) : "v"(x)); return r;
}
#define FEXP2(x) __fexp2_asm(x)
#endif

#define C2SCALE (0.17677669529663689f * 1.4426950408889634f)

// ---------------- LayerNorm + transpose, with cvt_weights folded in ----------------
__global__ __launch_bounds__(256) void ln_cvt_kernel(const float* __restrict__ x,
                                                     const float* __restrict__ nw,
                                                     const float* __restrict__ nb,
                                                     unsigned short* __restrict__ xn,
                                                     const float* __restrict__ qw,
                                                     const float* __restrict__ pw,
                                                     unsigned short* __restrict__ qwb,
                                                     unsigned short* __restrict__ pwb) {
  if (blockIdx.x >= 256) {
    const int t = (blockIdx.x - 256) * 256 + threadIdx.x;   // 0..65535
    const float4* src;
    unsigned short* dst;
    int idx;
    if (t < 49152) { src = reinterpret_cast<const float4*>(qw); dst = qwb; idx = t; }
    else           { src = reinterpret_cast<const float4*>(pw); dst = pwb; idx = t - 49152; }
    const float4 vv = src[idx];
    union { unsigned short u[4]; uint2 v; } pk;
    pk.u[0] = f2bf(vv.x); pk.u[1] = f2bf(vv.y); pk.u[2] = f2bf(vv.z); pk.u[3] = f2bf(vv.w);
    *reinterpret_cast<uint2*>(dst + 4 * idx) = pk.v;
    return;
  }

  __shared__ float Ls[256 * 32];
  __shared__ float Sred[2][32][8];
  __shared__ float Mrs[32][2];
  const int t  = threadIdx.x;
  const int n  = t & 31;
  const int cg = t >> 5;
  const int p0 = blockIdx.x * 32;
  const int b  = p0 >> 12;
  const int n0 = p0 & 4095;
  const float* xb = x + (size_t)b * CCH * NSEQ + n0;

  #pragma unroll
  for (int i = 0; i < 32; ++i) {
    const int c = i * 8 + cg;
    Ls[c * 32 + (n ^ (c & 31))] = xb[(size_t)c * NSEQ + n];
  }
  __syncthreads();

  float s = 0.f, sq = 0.f;
  #pragma unroll
  for (int j = 0; j < 32; ++j) {
    const int c = cg * 32 + j;
    const float v = Ls[c * 32 + (n ^ j)];
    s += v; sq += v * v;
  }
  Sred[0][n][cg] = s; Sred[1][n][cg] = sq;
  __syncthreads();
  float ts = 0.f, tq = 0.f;
  #pragma unroll
  for (int g = 0; g < 8; ++g) { ts += Sred[0][n][g]; tq += Sred[1][n][g]; }
  const float mean = ts * (1.f / 256.f);
  const float rstd = rsqrtf(tq * (1.f / 256.f) - mean * mean + 1e-5f);
  if (cg == 0) { Mrs[n][0] = mean; Mrs[n][1] = rstd; }
  __syncthreads();

  // coalesced write phase: thread -> (row n2, col-block c8b)
  const int n2  = t >> 3;        // 0..31
  const int c8b = t & 7;
  const float mean2 = Mrs[n2][0];
  const float rstd2 = Mrs[n2][1];
  unsigned short* orow = xn + ((size_t)b * NSEQ + n0 + n2) * CCH;
  #pragma unroll
  for (int j8 = 0; j8 < 4; ++j8) {
    const int cb = (j8 * 8 + c8b) * 8;        // 0..248, step 8
    unsigned int w_[4];
    #pragma unroll
    for (int hw = 0; hw < 4; ++hw) {
      const int c = cb + hw * 2;
      const float v0 = Ls[c * 32 + (n2 ^ (c & 31))];
      const float v1 = Ls[(c + 1) * 32 + (n2 ^ ((c + 1) & 31))];
      const float y0 = (v0 - mean2) * rstd2 * nw[c] + nb[c];
      const float y1 = (v1 - mean2) * rstd2 * nw[c + 1] + nb[c + 1];
      w_[hw] = pk_bf_rnd(y0, y1);
    }
    uint4 pkv; pkv.x = w_[0]; pkv.y = w_[1]; pkv.z = w_[2]; pkv.w = w_[3];
    *reinterpret_cast<uint4*>(orow + cb) = pkv;
  }
}

// ---------------- QKV GEMM: R16 stage-once (1 barrier, K=256 fully resident) ----------------
// Aux GEMMs are latency-bound: 8 barrier-crossings + 4 serialized VMEM exposures
// per block for operands that total 64KB. R16: stage A(64x256, 32KB) + B(64x256,
// 32KB) ONCE (16 uint4/thread, all in flight together), one barrier, then 32
// MFMAs + 40 ds_reads back-to-back (compiler fine-schedules via lgkmcnt).
// NOT the R8 failure: no loop-carried regs, no dbuf, no per-iter barrier.
// LDS 64KB -> 2 blocks/CU. Same MFMA order/operands -> bit-identical output.
__global__ __launch_bounds__(256, 2) void qkv_gemm(const unsigned short* __restrict__ xn,
                                                   const unsigned short* __restrict__ w,
                                                   const float* __restrict__ bias,
                                                   unsigned short* __restrict__ q,
                                                   unsigned short* __restrict__ k,
                                                   unsigned short* __restrict__ vt) {
  __shared__ unsigned short As[64 * 256];   // 32 KB, per-kb-section swizzled
  __shared__ unsigned short Bs[64 * 256];   // 32 KB
  const int tid = threadIdx.x;
  const int wv  = tid >> 6;
  const int lane = tid & 63;
  const int quad = lane >> 4, l16 = lane & 15;
  const int mt = blockIdx.x;   // 0..127
  const int nt = blockIdx.y;   // 0..11

  // stage-once: 8 chunks of A + 8 chunks of B per thread (16B each)
  #pragma unroll
  for (int j = 0; j < 8; ++j) {
    const int c = j * 256 + tid;            // 0..2047
    const int ar = c >> 5;                  // row 0..63
    const int rem = c & 31;
    const int kb = rem >> 3, acr = rem & 7;
    *reinterpret_cast<s8x*>(&As[ar * 256 + kb * 64 + ((acr ^ (ar & 7)) << 3)]) =
      *reinterpret_cast<const s8x*>(xn + (size_t)(mt * 64 + ar) * CCH + kb * 64 + acr * 8);
  }
  #pragma unroll
  for (int j = 0; j < 8; ++j) {
    const int c = j * 256 + tid;
    const int br = c >> 5;
    const int rem = c & 31;
    const int kb = rem >> 3, bcr = rem & 7;
    *reinterpret_cast<s8x*>(&Bs[br * 256 + kb * 64 + ((bcr ^ (br & 7)) << 3)]) =
      *reinterpret_cast<const s8x*>(w + (size_t)(nt * 64 + br) * CCH + kb * 64 + bcr * 8);
  }
  __syncthreads();

  f4x acc[4];
  #pragma unroll
  for (int ni = 0; ni < 4; ++ni)
    acc[ni] = (f4x){0.f, 0.f, 0.f, 0.f};

  #pragma unroll
  for (int kb = 0; kb < 4; ++kb) {
    #pragma unroll
    for (int kin = 0; kin < 2; ++kin) {
      const int chx = ((kin * 4 + quad) ^ (l16 & 7)) << 3;
      const s8x a0 = *reinterpret_cast<const s8x*>(&As[(wv * 16 + l16) * 256 + kb * 64 + chx]);
      #pragma unroll
      for (int ni = 0; ni < 4; ++ni) {
        const s8x bf = *reinterpret_cast<const s8x*>(&Bs[(ni * 16 + l16) * 256 + kb * 64 + chx]);
        acc[ni] = mfma16(a0, bf, acc[ni]);
      }
    }
  }

  const int sel = nt >> 2;                  // wave-uniform: 0=q 1=k 2=v
  #pragma unroll
  for (int ni = 0; ni < 4; ++ni) {
    const int o = nt * 64 + ni * 16 + l16;
    const float bs = bias[o];
    const int ol = o & 255;
    const int head = ol >> 5, d = ol & 31;
    const int g0 = mt * 64 + wv * 16 + quad * 4;
    const int bb = g0 >> 12, n0 = g0 & 4095;
    if (sel == 2) {
      unsigned short* vp = vt + ((size_t)(bb * NH + head) * HD + d) * NSEQ + n0;
      uint2 pk;
      pk.x = pk_bf_rnd(acc[ni][0] + bs, acc[ni][1] + bs);
      pk.y = pk_bf_rnd(acc[ni][2] + bs, acc[ni][3] + bs);
      *reinterpret_cast<uint2*>(vp) = pk;
    } else {
      const float sc = (sel == 0) ? C2SCALE : 1.f;
      unsigned short* base = (sel == 0) ? q : k;
      #pragma unroll
      for (int r = 0; r < 4; ++r)
        base[((size_t)(bb * NH + head) * NSEQ + n0 + r) * HD + d] = f2bf((acc[ni][r] + bs) * sc);
    }
  }
}

// ---------------- proj GEMM + residual: R16 stage-once (1 barrier) ----------------
// A 64x256 (32KB) + B 32x256 (16KB) = 48KB -> 3 blocks/CU. Same principle.
__global__ __launch_bounds__(256, 3) void proj_gemm(const unsigned short* __restrict__ xa,
                                                    const unsigned short* __restrict__ w,
                                                    const float* __restrict__ bias,
                                                    const float* __restrict__ gamma,
                                                    const float* __restrict__ x,
                                                    float* __restrict__ out) {
  __shared__ unsigned short As[64 * 256];   // 32 KB
  __shared__ unsigned short Bs[32 * 256];   // 16 KB
  const int tid = threadIdx.x;
  const int wv  = tid >> 6;
  const int lane = tid & 63;
  const int quad = lane >> 4, l16 = lane & 15;
  const int mt = blockIdx.x;   // 0..127
  const int nt = blockIdx.y;   // 0..7

  #pragma unroll
  for (int j = 0; j < 8; ++j) {
    const int c = j * 256 + tid;            // 0..2047
    const int ar = c >> 5;
    const int rem = c & 31;
    const int kb = rem >> 3, acr = rem & 7;
    *reinterpret_cast<s8x*>(&As[ar * 256 + kb * 64 + ((acr ^ (ar & 7)) << 3)]) =
      *reinterpret_cast<const s8x*>(xa + (size_t)(mt * 64 + ar) * CCH + kb * 64 + acr * 8);
  }
  #pragma unroll
  for (int j = 0; j < 4; ++j) {
    const int c = j * 256 + tid;            // 0..1023
    const int br = c >> 5;                  // row 0..31
    const int rem = c & 31;
    const int kb = rem >> 3, bcr = rem & 7;
    *reinterpret_cast<s8x*>(&Bs[br * 256 + kb * 64 + ((bcr ^ (br & 7)) << 3)]) =
      *reinterpret_cast<const s8x*>(w + (size_t)(nt * 32 + br) * CCH + kb * 64 + bcr * 8);
  }
  __syncthreads();

  f4x acc[2];
  acc[0] = (f4x){0.f, 0.f, 0.f, 0.f};
  acc[1] = (f4x){0.f, 0.f, 0.f, 0.f};

  #pragma unroll
  for (int kb = 0; kb < 4; ++kb) {
    #pragma unroll
    for (int kin = 0; kin < 2; ++kin) {
      const int chx = ((kin * 4 + quad) ^ (l16 & 7)) << 3;
      const s8x a0 = *reinterpret_cast<const s8x*>(&As[(wv * 16 + l16) * 256 + kb * 64 + chx]);
      #pragma unroll
      for (int ni = 0; ni < 2; ++ni) {
        const s8x bf = *reinterpret_cast<const s8x*>(&Bs[(ni * 16 + l16) * 256 + kb * 64 + chx]);
        acc[ni] = mfma16(a0, bf, acc[ni]);
      }
    }
  }

  const float g0 = gamma[0];
  #pragma unroll
  for (int ni = 0; ni < 2; ++ni) {
    const int c = nt * 32 + ni * 16 + l16;
    const float bs = bias[c];
    const int gr = mt * 64 + wv * 16 + quad * 4;
    const int bb = gr >> 12, n0 = gr & 4095;
    const size_t off = (size_t)(bb * CCH + c) * NSEQ + n0;
    const float4 xv = *reinterpret_cast<const float4*>(x + off);
    float4 ov;
    ov.x = g0 * (acc[ni][0] + bs) + xv.x;
    ov.y = g0 * (acc[ni][1] + bs) + xv.y;
    ov.z = g0 * (acc[ni][2] + bs) + xv.z;
    ov.w = g0 * (acc[ni][3] + bs) + xv.w;
    *reinterpret_cast<float4*>(out + off) = ov;
  }
}

// ---------------- Flash attention: R12 state (verbatim; conflicts=0, ~57us, declared done) ----------------
__global__ __launch_bounds__(256, 4) void fa_kernel(const unsigned short* __restrict__ q,
                                                    const unsigned short* __restrict__ k,
                                                    const unsigned short* __restrict__ vt,
                                                    float* __restrict__ Opart,
                                                    float* __restrict__ Lpart) {
  __shared__ unsigned short Kf[2][2048];   // 4 frags x 64 lanes x 8 shorts, 4KB each
  __shared__ unsigned short Vf[2][2048];   // 4 frags x 64 lanes x 8 shorts
  __shared__ unsigned short Pf[8192];      // 4 waves x 8 wgroups x 64 lanes x 4 shorts, 16KB

  const int tid  = threadIdx.x;
  const int wv   = tid >> 6;
  const int lane = tid & 63;
  const int quad = lane >> 4;
  const int l16  = lane & 15;
  const int i    = blockIdx.x;
  const int bh   = i & 15;          // XCD pinning
  const int rest = i >> 4;          // 0..63
  const int half = rest & 1;
  const int qblk = rest >> 1;       // 0..31
  const int kv0  = half * 2048;     // this block's KV range: [kv0, kv0+2048)

  const unsigned short* kb_ = k  + ((size_t)bh * NSEQ + kv0) * HD;
  const unsigned short* vb_ = vt + (size_t)bh * HD * NSEQ + kv0;

  // staging assignment: thread tid <-> fragment slot tid
  const int kfrow = (tid >> 6) * 16 + (tid & 15);
  const int kfcol = ((tid >> 4) & 3) * 8;
  const int vfrow = ((tid >> 7) & 1) * 16 + (tid & 15);
  const int vfcol = ((tid >> 6) & 1) * 32 + ((tid >> 4) & 3) * 8;

  s8x bq0, bq1;
  {
    const unsigned short* qb = q + ((size_t)bh * NSEQ + (size_t)qblk * 128 + wv * 32) * HD;
    bq0 = *reinterpret_cast<const s8x*>(qb + (size_t)l16 * HD + quad * 8);
    bq1 = *reinterpret_cast<const s8x*>(qb + (size_t)(16 + l16) * HD + quad * 8);
  }

  // prologue: stage tile 0, then issue loads for tile 1
  uint4 kreg = *reinterpret_cast<const uint4*>(kb_ + (size_t)kfrow * HD + kfcol);
  uint4 vreg = *reinterpret_cast<const uint4*>(vb_ + (size_t)vfrow * NSEQ + vfcol);
  *reinterpret_cast<uint4*>(&Kf[0][tid * 8]) = kreg;
  *reinterpret_cast<uint4*>(&Vf[0][tid * 8]) = vreg;
  kreg = *reinterpret_cast<const uint4*>(kb_ + (size_t)(64 + kfrow) * HD + kfcol);
  vreg = *reinterpret_cast<const uint4*>(vb_ + (size_t)vfrow * NSEQ + 64 + vfcol);
  __syncthreads();

  // S(0) from Kf[0]
  f4x st[4][2];
  #pragma unroll
  for (int ii = 0; ii < 4; ++ii) {
    const s8x ak = *reinterpret_cast<const s8x*>(&Kf[0][(ii * 64 + lane) * 8]);
    const f4x z = {0.f, 0.f, 0.f, 0.f};
    st[ii][0] = mfma16(ak, bq0, z);
    st[ii][1] = mfma16(ak, bq1, z);
  }

  f4x oacc[2][2];
  #pragma unroll
  for (int dt = 0; dt < 2; ++dt)
    #pragma unroll
    for (int ct = 0; ct < 2; ++ct)
      oacc[dt][ct] = (f4x){0.f, 0.f, 0.f, 0.f};
  f4x accL[2] = {(f4x){0.f, 0.f, 0.f, 0.f}, (f4x){0.f, 0.f, 0.f, 0.f}};

  s8x ones;
  #pragma unroll
  for (int j = 0; j < 8; ++j) ones[j] = (short)0x3F80;   // bf16 1.0

  const int pbase = wv * 2048;   // this wave's Pf region (shorts)

  // P-read slot0 per fragment f (reader lane = quad,l16):
  //   slot0(f) = ((f&1)*4 + (f>>1)*2 + (quad>>1))*64 + (quad&1)*32 + l16
  int pslot0[4];
  #pragma unroll
  for (int f = 0; f < 4; ++f)
    pslot0[f] = (((f & 1) * 4 + (f >> 1) * 2 + (quad >> 1)) * 64 + (quad & 1) * 32 + l16) * 4;

  s8x vavr[4];   // V(t) fragments carried in regs for next iter's lagged PV

  for (int t = 0; t < 32; ++t) {
    const int c = t & 1;

    // ---- A: read P(t-1) fragments (precede this iter's P writes; in-order LDS) ----
    s8x bp[4];
    if (t > 0) {
      #pragma unroll
      for (int j = 0; j < 4; ++j) {
        union { uint4 u; s8x v; } tmp;
        const uint2 p0 = *reinterpret_cast<const uint2*>(&Pf[pbase + pslot0[j]]);
        const uint2 p1 = *reinterpret_cast<const uint2*>(&Pf[pbase + pslot0[j] + 64]);
        tmp.u.x = p0.x; tmp.u.y = p0.y; tmp.u.z = p1.x; tmp.u.w = p1.y;
        bp[j] = tmp.v;
      }
    }

    // ---- B: write staged tile t+1 into the back buffers (contiguous 1KB/wave) ----
    if (t + 1 < 32) {
      *reinterpret_cast<uint4*>(&Kf[c ^ 1][tid * 8]) = kreg;
      *reinterpret_cast<uint4*>(&Vf[c ^ 1][tid * 8]) = vreg;
    }

    // ---- D: PV(t-1) MFMAs (independent of exp below; overlaps on MFMA pipe) ----
    if (t > 0) {
      #pragma unroll
      for (int kb2 = 0; kb2 < 2; ++kb2) {
        oacc[0][0] = mfma16(vavr[kb2],     bp[2 * kb2],     oacc[0][0]);
        oacc[1][0] = mfma16(vavr[2 + kb2], bp[2 * kb2],     oacc[1][0]);
        oacc[0][1] = mfma16(vavr[kb2],     bp[2 * kb2 + 1], oacc[0][1]);
        oacc[1][1] = mfma16(vavr[2 + kb2], bp[2 * kb2 + 1], oacc[1][1]);
        accL[0] = mfma16(ones, bp[2 * kb2],     accL[0]);
        accL[1] = mfma16(ones, bp[2 * kb2 + 1], accL[1]);
      }
    }

    // ---- C+E: exp(t) + pack + write P(t) writer-major (contiguous 512B/instr) ----
    #pragma unroll
    for (int ct = 0; ct < 2; ++ct) {
      #pragma unroll
      for (int ii = 0; ii < 4; ++ii) {
        const float e0 = FEXP2(st[ii][ct][0]);
        const float e1 = FEXP2(st[ii][ct][1]);
        const float e2 = FEXP2(st[ii][ct][2]);
        const float e3 = FEXP2(st[ii][ct][3]);
        uint2 pw;
        pw.x = pk_bf_trunc(e0, e1);
        pw.y = pk_bf_trunc(e2, e3);
        *reinterpret_cast<uint2*>(&Pf[pbase + ((ct * 4 + ii) * 64 + lane) * 4]) = pw;
      }
    }

    // ---- F: issue global loads for tile t+2 (loop-carried: cannot be sunk) ----
    if (t + 2 < 32) {
      kreg = *reinterpret_cast<const uint4*>(kb_ + (size_t)((t + 2) * 64 + kfrow) * HD + kfcol);
      vreg = *reinterpret_cast<const uint4*>(vb_ + (size_t)vfrow * NSEQ + (t + 2) * 64 + vfcol);
    }

    // ---- G: V(t) fragments -> regs from FRONT buffer (race-free, contiguous) ----
    #pragma unroll
    for (int j = 0; j < 4; ++j)
      vavr[j] = *reinterpret_cast<const s8x*>(&Vf[c][(j * 64 + lane) * 8]);

    __syncthreads();   // back buffers fully written; fronts fully read

    // ---- I: S(t+1) from the freshly staged K buffer ----
    if (t + 1 < 32) {
      #pragma unroll
      for (int ii = 0; ii < 4; ++ii) {
        const s8x ak = *reinterpret_cast<const s8x*>(&Kf[c ^ 1][(ii * 64 + lane) * 8]);
        const f4x z = {0.f, 0.f, 0.f, 0.f};
        st[ii][0] = mfma16(ak, bq0, z);
        st[ii][1] = mfma16(ak, bq1, z);
      }
    }
  }

  // ---- epilogue: PV(31) (P(31) in Pf writer-major, V(31) in vavr) ----
  {
    s8x bp[4];
    #pragma unroll
    for (int j = 0; j < 4; ++j) {
      union { uint4 u; s8x v; } tmp;
      const uint2 p0 = *reinterpret_cast<const uint2*>(&Pf[pbase + pslot0[j]]);
      const uint2 p1 = *reinterpret_cast<const uint2*>(&Pf[pbase + pslot0[j] + 64]);
      tmp.u.x = p0.x; tmp.u.y = p0.y; tmp.u.z = p1.x; tmp.u.w = p1.y;
      bp[j] = tmp.v;
    }
    #pragma unroll
    for (int kb2 = 0; kb2 < 2; ++kb2) {
      oacc[0][0] = mfma16(vavr[kb2],     bp[2 * kb2],     oacc[0][0]);
      oacc[1][0] = mfma16(vavr[2 + kb2], bp[2 * kb2],     oacc[1][0]);
      oacc[0][1] = mfma16(vavr[kb2],     bp[2 * kb2 + 1], oacc[0][1]);
      oacc[1][1] = mfma16(vavr[2 + kb2], bp[2 * kb2 + 1], oacc[1][1]);
      accL[0] = mfma16(ones, bp[2 * kb2],     accL[0]);
      accL[1] = mfma16(ones, bp[2 * kb2 + 1], accL[1]);
    }
  }

  // ---- epilogue: store partial O (f32) and partial l ----
  #pragma unroll
  for (int ct = 0; ct < 2; ++ct) {
    const int qg = qblk * 128 + wv * 32 + ct * 16 + l16;
    float* obase = Opart + ((size_t)(half * 16 + bh) * NSEQ + qg) * HD;
    #pragma unroll
    for (int dt = 0; dt < 2; ++dt) {
      float4 ov;
      ov.x = oacc[dt][ct][0]; ov.y = oacc[dt][ct][1];
      ov.z = oacc[dt][ct][2]; ov.w = oacc[dt][ct][3];
      *reinterpret_cast<float4*>(obase + dt * 16 + quad * 4) = ov;
    }
    if (quad == 0)
      Lpart[(size_t)(half * 16 + bh) * NSEQ + qg] = accL[ct][0];
  }
}

// ---------------- combine the two KV-halves: O=(O0+O1)/(l0+l1), write bf16 xa ----------------
__global__ __launch_bounds__(256) void fa_combine(const float* __restrict__ Opart,
                                                  const float* __restrict__ Lpart,
                                                  unsigned short* __restrict__ xa) {
  const int t  = blockIdx.x * 256 + threadIdx.x;   // 0..262143
  const int c8 = t & 3;                            // col group of 8
  const int n  = (t >> 2) & 4095;
  const int bh = t >> 14;
  const int b  = bh >> 3, h = bh & 7;

  const size_t o0 = ((size_t)bh * NSEQ + n) * HD + c8 * 8;
  const size_t o1 = o0 + (size_t)16 * NSEQ * HD;
  const float4 a0 = *reinterpret_cast<const float4*>(Opart + o0);
  const float4 a1 = *reinterpret_cast<const float4*>(Opart + o0 + 4);
  const float4 b0 = *reinterpret_cast<const float4*>(Opart + o1);
  const float4 b1 = *reinterpret_cast<const float4*>(Opart + o1 + 4);
  const float l0 = Lpart[(size_t)bh * NSEQ + n];
  const float l1 = Lpart[(size_t)(16 + bh) * NSEQ + n];
  const float rl = 1.f / (l0 + l1);

  uint4 ow;
  ow.x = pk_bf_rnd((a0.x + b0.x) * rl, (a0.y + b0.y) * rl);
  ow.y = pk_bf_rnd((a0.z + b0.z) * rl, (a0.w + b0.w) * rl);
  ow.z = pk_bf_rnd((a1.x + b1.x) * rl, (a1.y + b1.y) * rl);
  ow.w = pk_bf_rnd((a1.z + b1.z) * rl, (a1.w + b1.w) * rl);
  *reinterpret_cast<uint4*>(xa + ((size_t)b * NSEQ + n) * CCH + h * HD + c8 * 8) = ow;
}

extern "C" void kernel_launch(void* const* d_in, const int* in_sizes, int n_in,
                              void* d_out, int out_size, void* d_ws, size_t ws_size,
                              hipStream_t stream) {
  const float* x      = (const float*)d_in[0];
  const float* norm_w = (const float*)d_in[1];
  const float* norm_b = (const float*)d_in[2];
  const float* qkv_w  = (const float*)d_in[3];
  const float* qkv_b  = (const float*)d_in[4];
  const float* proj_w = (const float*)d_in[5];
  const float* proj_b = (const float*)d_in[6];
  const float* gamma  = (const float*)d_in[7];
  float* out = (float*)d_out;

  char* ws = (char*)d_ws;
  unsigned short* xn  = (unsigned short*)(ws);              // (B,N,C) bf16, 4 MiB
  unsigned short* qwb = (unsigned short*)(ws + 4194304);
  unsigned short* pwb = (unsigned short*)(ws + 4587520);
  unsigned short* q   = (unsigned short*)(ws + 4718592);    // (B,NH,N,HD), pre-scaled
  unsigned short* k   = (unsigned short*)(ws + 8912896);    // (B,NH,N,HD)
  unsigned short* vt  = (unsigned short*)(ws + 13107200);   // (B,NH,HD,N)
  unsigned short* xa  = (unsigned short*)(ws + 17301504);   // (B,N,C) bf16, 4 MiB
  float* Opart        = (float*)(ws + 21495808);            // [2][16][N][HD] f32, 16 MiB
  float* Lpart        = (float*)(ws + 38273024);            // [2][16][N] f32, 512 KiB

  hipLaunchKernelGGL(ln_cvt_kernel, dim3(512), dim3(256), 0, stream,
                     x, norm_w, norm_b, xn, qkv_w, proj_w, qwb, pwb);
  hipLaunchKernelGGL(qkv_gemm,  dim3(128, 12), dim3(256), 0, stream, xn, qwb, qkv_b, q, k, vt);
  hipLaunchKernelGGL(fa_kernel, dim3(1024), dim3(256), 0, stream, q, k, vt, Opart, Lpart);
  hipLaunchKernelGGL(fa_combine, dim3(1024), dim3(256), 0, stream, Opart, Lpart, xa);
  hipLaunchKernelGGL(proj_gemm, dim3(128, 8), dim3(256), 0, stream, xa, pwb, proj_b, gamma, x, out);
}

// Round 18
// 144.496 us; speedup vs baseline: 1.0192x; 1.0192x over previous
//
#include <hip/hip_runtime.h>

#define CCH   256
#define NSEQ  4096
#define NH    8
#define HD    32

typedef short s8x __attribute__((ext_vector_type(8)));
typedef float f4x __attribute__((ext_vector_type(4)));

__device__ __forceinline__ f4x mfma16(s8x a, s8x b, f4x c) {
  return __builtin_amdgcn_mfma_f32_16x16x32_bf16(a, b, c, 0, 0, 0);
}

__device__ __forceinline__ unsigned short f2bf(float f) {
  union { float f; unsigned int u; } v; v.f = f;
  unsigned int u = v.u + 0x7fffu + ((v.u >> 16) & 1u);
  return (unsigned short)(u >> 16);
}

__device__ __forceinline__ unsigned int pk_bf_rnd(float lo, float hi) {
  return (unsigned int)f2bf(lo) | ((unsigned int)f2bf(hi) << 16);
}

// pack two f32 -> one u32 of bf16 (truncating; P >= 0 so safe)
__device__ __forceinline__ unsigned int pk_bf_trunc(float lo, float hi) {
  union { float f; unsigned int u; } a, b; a.f = lo; b.f = hi;
  return __builtin_amdgcn_perm(b.u, a.u, 0x07060302);
}

// raw v_exp_f32
#if defined(__has_builtin)
#if __has_builtin(__builtin_amdgcn_exp2f)
#define FEXP2(x) __builtin_amdgcn_exp2f(x)
#endif
#endif
#ifndef FEXP2
__device__ __forceinline__ float __fexp2_asm(float x) {
  float r; asm("v_exp_f32 %0, %1" : "=v"(r) : "v"(x)); return r;
}
#define FEXP2(x) __fexp2_asm(x)
#endif

#define C2SCALE (0.17677669529663689f * 1.4426950408889634f)

// ---------------- LayerNorm + transpose, with cvt_weights folded in ----------------
__global__ __launch_bounds__(256) void ln_cvt_kernel(const float* __restrict__ x,
                                                     const float* __restrict__ nw,
                                                     const float* __restrict__ nb,
                                                     unsigned short* __restrict__ xn,
                                                     const float* __restrict__ qw,
                                                     const float* __restrict__ pw,
                                                     unsigned short* __restrict__ qwb,
                                                     unsigned short* __restrict__ pwb) {
  if (blockIdx.x >= 256) {
    const int t = (blockIdx.x - 256) * 256 + threadIdx.x;   // 0..65535
    const float4* src;
    unsigned short* dst;
    int idx;
    if (t < 49152) { src = reinterpret_cast<const float4*>(qw); dst = qwb; idx = t; }
    else           { src = reinterpret_cast<const float4*>(pw); dst = pwb; idx = t - 49152; }
    const float4 vv = src[idx];
    union { unsigned short u[4]; uint2 v; } pk;
    pk.u[0] = f2bf(vv.x); pk.u[1] = f2bf(vv.y); pk.u[2] = f2bf(vv.z); pk.u[3] = f2bf(vv.w);
    *reinterpret_cast<uint2*>(dst + 4 * idx) = pk.v;
    return;
  }

  __shared__ float Ls[256 * 32];
  __shared__ float Sred[2][32][8];
  __shared__ float Mrs[32][2];
  const int t  = threadIdx.x;
  const int n  = t & 31;
  const int cg = t >> 5;
  const int p0 = blockIdx.x * 32;
  const int b  = p0 >> 12;
  const int n0 = p0 & 4095;
  const float* xb = x + (size_t)b * CCH * NSEQ + n0;

  #pragma unroll
  for (int i = 0; i < 32; ++i) {
    const int c = i * 8 + cg;
    Ls[c * 32 + (n ^ (c & 31))] = xb[(size_t)c * NSEQ + n];
  }
  __syncthreads();

  float s = 0.f, sq = 0.f;
  #pragma unroll
  for (int j = 0; j < 32; ++j) {
    const int c = cg * 32 + j;
    const float v = Ls[c * 32 + (n ^ j)];
    s += v; sq += v * v;
  }
  Sred[0][n][cg] = s; Sred[1][n][cg] = sq;
  __syncthreads();
  float ts = 0.f, tq = 0.f;
  #pragma unroll
  for (int g = 0; g < 8; ++g) { ts += Sred[0][n][g]; tq += Sred[1][n][g]; }
  const float mean = ts * (1.f / 256.f);
  const float rstd = rsqrtf(tq * (1.f / 256.f) - mean * mean + 1e-5f);
  if (cg == 0) { Mrs[n][0] = mean; Mrs[n][1] = rstd; }
  __syncthreads();

  // coalesced write phase: thread -> (row n2, col-block c8b)
  const int n2  = t >> 3;        // 0..31
  const int c8b = t & 7;
  const float mean2 = Mrs[n2][0];
  const float rstd2 = Mrs[n2][1];
  unsigned short* orow = xn + ((size_t)b * NSEQ + n0 + n2) * CCH;
  #pragma unroll
  for (int j8 = 0; j8 < 4; ++j8) {
    const int cb = (j8 * 8 + c8b) * 8;        // 0..248, step 8
    unsigned int w_[4];
    #pragma unroll
    for (int hw = 0; hw < 4; ++hw) {
      const int c = cb + hw * 2;
      const float v0 = Ls[c * 32 + (n2 ^ (c & 31))];
      const float v1 = Ls[(c + 1) * 32 + (n2 ^ ((c + 1) & 31))];
      const float y0 = (v0 - mean2) * rstd2 * nw[c] + nb[c];
      const float y1 = (v1 - mean2) * rstd2 * nw[c + 1] + nb[c + 1];
      w_[hw] = pk_bf_rnd(y0, y1);
    }
    uint4 pkv; pkv.x = w_[0]; pkv.y = w_[1]; pkv.z = w_[2]; pkv.w = w_[3];
    *reinterpret_cast<uint4*>(orow + cb) = pkv;
  }
}

// ---------------- QKV GEMM: 64x64 tiles (R10 state) ----------------
__global__ __launch_bounds__(256, 6) void qkv_gemm(const unsigned short* __restrict__ xn,
                                                   const unsigned short* __restrict__ w,
                                                   const float* __restrict__ bias,
                                                   unsigned short* __restrict__ q,
                                                   unsigned short* __restrict__ k,
                                                   unsigned short* __restrict__ vt) {
  __shared__ unsigned short As[64 * 64];
  __shared__ unsigned short Bs[64 * 64];
  const int tid = threadIdx.x;
  const int wv  = tid >> 6;
  const int lane = tid & 63;
  const int quad = lane >> 4, l16 = lane & 15;
  const int mt = blockIdx.x;   // 0..127
  const int nt = blockIdx.y;   // 0..11

  f4x acc[4];
  #pragma unroll
  for (int ni = 0; ni < 4; ++ni)
    acc[ni] = (f4x){0.f, 0.f, 0.f, 0.f};

  for (int kb = 0; kb < 4; ++kb) {
    if (kb) __syncthreads();
    #pragma unroll
    for (int j = 0; j < 2; ++j) {
      const int c = j * 256 + tid;
      const int ar = c >> 3, acr = c & 7;
      *reinterpret_cast<s8x*>(&As[ar * 64 + ((acr ^ (ar & 7)) << 3)]) =
        *reinterpret_cast<const s8x*>(xn + (size_t)(mt * 64 + ar) * CCH + kb * 64 + acr * 8);
    }
    #pragma unroll
    for (int j = 0; j < 2; ++j) {
      const int c = j * 256 + tid;
      const int br = c >> 3, bcr = c & 7;
      *reinterpret_cast<s8x*>(&Bs[br * 64 + ((bcr ^ (br & 7)) << 3)]) =
        *reinterpret_cast<const s8x*>(w + (size_t)(nt * 64 + br) * CCH + kb * 64 + bcr * 8);
    }
    __syncthreads();
    #pragma unroll
    for (int kin = 0; kin < 2; ++kin) {
      const int chx = ((kin * 4 + quad) ^ (l16 & 7)) << 3;
      const s8x a0 = *reinterpret_cast<const s8x*>(&As[(wv * 16 + l16) * 64 + chx]);
      #pragma unroll
      for (int ni = 0; ni < 4; ++ni) {
        const s8x bf = *reinterpret_cast<const s8x*>(&Bs[(ni * 16 + l16) * 64 + chx]);
        acc[ni] = mfma16(a0, bf, acc[ni]);
      }
    }
  }

  const int sel = nt >> 2;                  // wave-uniform: 0=q 1=k 2=v
  #pragma unroll
  for (int ni = 0; ni < 4; ++ni) {
    const int o = nt * 64 + ni * 16 + l16;
    const float bs = bias[o];
    const int ol = o & 255;
    const int head = ol >> 5, d = ol & 31;
    const int g0 = mt * 64 + wv * 16 + quad * 4;
    const int bb = g0 >> 12, n0 = g0 & 4095;
    if (sel == 2) {
      unsigned short* vp = vt + ((size_t)(bb * NH + head) * HD + d) * NSEQ + n0;
      uint2 pk;
      pk.x = pk_bf_rnd(acc[ni][0] + bs, acc[ni][1] + bs);
      pk.y = pk_bf_rnd(acc[ni][2] + bs, acc[ni][3] + bs);
      *reinterpret_cast<uint2*>(vp) = pk;
    } else {
      const float sc = (sel == 0) ? C2SCALE : 1.f;
      unsigned short* base = (sel == 0) ? q : k;
      #pragma unroll
      for (int r = 0; r < 4; ++r)
        base[((size_t)(bb * NH + head) * NSEQ + n0 + r) * HD + d] = f2bf((acc[ni][r] + bs) * sc);
    }
  }
}

// ---------------- proj GEMM + residual: 64x32 tiles (R10 state) ----------------
__global__ __launch_bounds__(256, 6) void proj_gemm(const unsigned short* __restrict__ xa,
                                                    const unsigned short* __restrict__ w,
                                                    const float* __restrict__ bias,
                                                    const float* __restrict__ gamma,
                                                    const float* __restrict__ x,
                                                    float* __restrict__ out) {
  __shared__ unsigned short As[64 * 64];
  __shared__ unsigned short Bs[32 * 64];
  const int tid = threadIdx.x;
  const int wv  = tid >> 6;
  const int lane = tid & 63;
  const int quad = lane >> 4, l16 = lane & 15;
  const int mt = blockIdx.x;   // 0..127
  const int nt = blockIdx.y;   // 0..7

  f4x acc[2];
  acc[0] = (f4x){0.f, 0.f, 0.f, 0.f};
  acc[1] = (f4x){0.f, 0.f, 0.f, 0.f};

  for (int kb = 0; kb < 4; ++kb) {
    if (kb) __syncthreads();
    #pragma unroll
    for (int j = 0; j < 2; ++j) {
      const int c = j * 256 + tid;
      const int ar = c >> 3, acr = c & 7;
      *reinterpret_cast<s8x*>(&As[ar * 64 + ((acr ^ (ar & 7)) << 3)]) =
        *reinterpret_cast<const s8x*>(xa + (size_t)(mt * 64 + ar) * CCH + kb * 64 + acr * 8);
    }
    {
      const int c = tid;                      // 32*64 shorts = exactly 1 s8x/thread
      const int br = c >> 3, bcr = c & 7;
      *reinterpret_cast<s8x*>(&Bs[br * 64 + ((bcr ^ (br & 7)) << 3)]) =
        *reinterpret_cast<const s8x*>(w + (size_t)(nt * 32 + br) * CCH + kb * 64 + bcr * 8);
    }
    __syncthreads();
    #pragma unroll
    for (int kin = 0; kin < 2; ++kin) {
      const int chx = ((kin * 4 + quad) ^ (l16 & 7)) << 3;
      const s8x a0 = *reinterpret_cast<const s8x*>(&As[(wv * 16 + l16) * 64 + chx]);
      #pragma unroll
      for (int ni = 0; ni < 2; ++ni) {
        const s8x bf = *reinterpret_cast<const s8x*>(&Bs[(ni * 16 + l16) * 64 + chx]);
        acc[ni] = mfma16(a0, bf, acc[ni]);
      }
    }
  }

  const float g0 = gamma[0];
  #pragma unroll
  for (int ni = 0; ni < 2; ++ni) {
    const int c = nt * 32 + ni * 16 + l16;
    const float bs = bias[c];
    const int gr = mt * 64 + wv * 16 + quad * 4;
    const int bb = gr >> 12, n0 = gr & 4095;
    const size_t off = (size_t)(bb * CCH + c) * NSEQ + n0;
    const float4 xv = *reinterpret_cast<const float4*>(x + off);
    float4 ov;
    ov.x = g0 * (acc[ni][0] + bs) + xv.x;
    ov.y = g0 * (acc[ni][1] + bs) + xv.y;
    ov.z = g0 * (acc[ni][2] + bs) + xv.z;
    ov.w = g0 * (acc[ni][3] + bs) + xv.w;
    *reinterpret_cast<float4*>(out + off) = ov;
  }
}

// ---------------- Flash attention: R9 pipeline + fragment-major LDS (R11 state, 143.2us best) ----------------
// Fragment-major K/V/P layouts: every fragment read and staging write is a
// contiguous wave access; conflicts 1.15e7 -> 4.19e6. (R12 writer-major variant
// reached 0 conflicts at identical time; R11 holds the best measured TOTAL.)
__global__ __launch_bounds__(256, 4) void fa_kernel(const unsigned short* __restrict__ q,
                                                    const unsigned short* __restrict__ k,
                                                    const unsigned short* __restrict__ vt,
                                                    float* __restrict__ Opart,
                                                    float* __restrict__ Lpart) {
  __shared__ unsigned short Kf[2][2048];   // 4 frags x 64 lanes x 8 shorts, 4KB each
  __shared__ unsigned short Vf[2][2048];   // 4 frags x 64 lanes x 8 shorts
  __shared__ unsigned short Pf[8192];      // 4 waves x 4 frags x 64 lanes x 8 shorts, 16KB

  const int tid  = threadIdx.x;
  const int wv   = tid >> 6;
  const int lane = tid & 63;
  const int quad = lane >> 4;
  const int l16  = lane & 15;
  const int i    = blockIdx.x;
  const int bh   = i & 15;          // XCD pinning
  const int rest = i >> 4;          // 0..63
  const int half = rest & 1;
  const int qblk = rest >> 1;       // 0..31
  const int kv0  = half * 2048;     // this block's KV range: [kv0, kv0+2048)

  const unsigned short* kb_ = k  + ((size_t)bh * NSEQ + kv0) * HD;
  const unsigned short* vb_ = vt + (size_t)bh * HD * NSEQ + kv0;

  // staging assignment: thread tid <-> fragment slot tid
  const int kfrow = (tid >> 6) * 16 + (tid & 15);
  const int kfcol = ((tid >> 4) & 3) * 8;
  const int vfrow = ((tid >> 7) & 1) * 16 + (tid & 15);
  const int vfcol = ((tid >> 6) & 1) * 32 + ((tid >> 4) & 3) * 8;

  s8x bq0, bq1;
  {
    const unsigned short* qb = q + ((size_t)bh * NSEQ + (size_t)qblk * 128 + wv * 32) * HD;
    bq0 = *reinterpret_cast<const s8x*>(qb + (size_t)l16 * HD + quad * 8);
    bq1 = *reinterpret_cast<const s8x*>(qb + (size_t)(16 + l16) * HD + quad * 8);
  }

  // prologue: stage tile 0, then issue loads for tile 1
  uint4 kreg = *reinterpret_cast<const uint4*>(kb_ + (size_t)kfrow * HD + kfcol);
  uint4 vreg = *reinterpret_cast<const uint4*>(vb_ + (size_t)vfrow * NSEQ + vfcol);
  *reinterpret_cast<uint4*>(&Kf[0][tid * 8]) = kreg;
  *reinterpret_cast<uint4*>(&Vf[0][tid * 8]) = vreg;
  kreg = *reinterpret_cast<const uint4*>(kb_ + (size_t)(64 + kfrow) * HD + kfcol);
  vreg = *reinterpret_cast<const uint4*>(vb_ + (size_t)vfrow * NSEQ + 64 + vfcol);
  __syncthreads();

  // S(0) from Kf[0]
  f4x st[4][2];
  #pragma unroll
  for (int ii = 0; ii < 4; ++ii) {
    const s8x ak = *reinterpret_cast<const s8x*>(&Kf[0][(ii * 64 + lane) * 8]);
    const f4x z = {0.f, 0.f, 0.f, 0.f};
    st[ii][0] = mfma16(ak, bq0, z);
    st[ii][1] = mfma16(ak, bq1, z);
  }

  f4x oacc[2][2];
  #pragma unroll
  for (int dt = 0; dt < 2; ++dt)
    #pragma unroll
    for (int ct = 0; ct < 2; ++ct)
      oacc[dt][ct] = (f4x){0.f, 0.f, 0.f, 0.f};
  f4x accL[2] = {(f4x){0.f, 0.f, 0.f, 0.f}, (f4x){0.f, 0.f, 0.f, 0.f}};

  s8x ones;
  #pragma unroll
  for (int j = 0; j < 8; ++j) ones[j] = (short)0x3F80;   // bf16 1.0

  const int pbase = wv * 4 * 64 * 8;   // this wave's Pf region (shorts)

  s8x vavr[4];   // V(t) fragments carried in regs for next iter's lagged PV

  for (int t = 0; t < 32; ++t) {
    const int c = t & 1;

    // ---- A: read P(t-1) fragments (precede this iter's P writes; in-order LDS) ----
    s8x bp[4];
    if (t > 0) {
      #pragma unroll
      for (int j = 0; j < 4; ++j)
        bp[j] = *reinterpret_cast<const s8x*>(&Pf[pbase + (j * 64 + lane) * 8]);
    }

    // ---- B: write staged tile t+1 into the back buffers (contiguous 1KB/wave) ----
    if (t + 1 < 32) {
      *reinterpret_cast<uint4*>(&Kf[c ^ 1][tid * 8]) = kreg;
      *reinterpret_cast<uint4*>(&Vf[c ^ 1][tid * 8]) = vreg;
    }

    // ---- D: PV(t-1) MFMAs (independent of exp below; overlaps on MFMA pipe) ----
    if (t > 0) {
      #pragma unroll
      for (int kb2 = 0; kb2 < 2; ++kb2) {
        oacc[0][0] = mfma16(vavr[kb2],     bp[2 * kb2],     oacc[0][0]);
        oacc[1][0] = mfma16(vavr[2 + kb2], bp[2 * kb2],     oacc[1][0]);
        oacc[0][1] = mfma16(vavr[kb2],     bp[2 * kb2 + 1], oacc[0][1]);
        oacc[1][1] = mfma16(vavr[2 + kb2], bp[2 * kb2 + 1], oacc[1][1]);
        accL[0] = mfma16(ones, bp[2 * kb2],     accL[0]);
        accL[1] = mfma16(ones, bp[2 * kb2 + 1], accL[1]);
      }
    }

    // ---- C+E: exp(t) + pack + write P(t) fragment-major (after A: safe) ----
    #pragma unroll
    for (int ct = 0; ct < 2; ++ct) {
      #pragma unroll
      for (int ii = 0; ii < 4; ++ii) {
        const float e0 = FEXP2(st[ii][ct][0]);
        const float e1 = FEXP2(st[ii][ct][1]);
        const float e2 = FEXP2(st[ii][ct][2]);
        const float e3 = FEXP2(st[ii][ct][3]);
        uint2 pw;
        pw.x = pk_bf_trunc(e0, e1);
        pw.y = pk_bf_trunc(e2, e3);
        // frag f = (ii>>1)*2 + ct; lane' = ((ii&1)*2 + (quad>>1))*16 + l16; piece = (quad&1)*4
        const int paddr = pbase + (((ii >> 1) * 2 + ct) * 64 + ((ii & 1) * 2 + (quad >> 1)) * 16 + l16) * 8 + (quad & 1) * 4;
        *reinterpret_cast<uint2*>(&Pf[paddr]) = pw;
      }
    }

    // ---- F: issue global loads for tile t+2 (loop-carried: cannot be sunk) ----
    if (t + 2 < 32) {
      kreg = *reinterpret_cast<const uint4*>(kb_ + (size_t)((t + 2) * 64 + kfrow) * HD + kfcol);
      vreg = *reinterpret_cast<const uint4*>(vb_ + (size_t)vfrow * NSEQ + (t + 2) * 64 + vfcol);
    }

    // ---- G: V(t) fragments -> regs from FRONT buffer (race-free, contiguous) ----
    #pragma unroll
    for (int j = 0; j < 4; ++j)
      vavr[j] = *reinterpret_cast<const s8x*>(&Vf[c][(j * 64 + lane) * 8]);

    __syncthreads();   // back buffers fully written; fronts fully read

    // ---- I: S(t+1) from the freshly staged K buffer ----
    if (t + 1 < 32) {
      #pragma unroll
      for (int ii = 0; ii < 4; ++ii) {
        const s8x ak = *reinterpret_cast<const s8x*>(&Kf[c ^ 1][(ii * 64 + lane) * 8]);
        const f4x z = {0.f, 0.f, 0.f, 0.f};
        st[ii][0] = mfma16(ak, bq0, z);
        st[ii][1] = mfma16(ak, bq1, z);
      }
    }
  }

  // ---- epilogue: PV(31) (P(31) in Pf, V(31) in vavr) ----
  {
    s8x bp[4];
    #pragma unroll
    for (int j = 0; j < 4; ++j)
      bp[j] = *reinterpret_cast<const s8x*>(&Pf[pbase + (j * 64 + lane) * 8]);
    #pragma unroll
    for (int kb2 = 0; kb2 < 2; ++kb2) {
      oacc[0][0] = mfma16(vavr[kb2],     bp[2 * kb2],     oacc[0][0]);
      oacc[1][0] = mfma16(vavr[2 + kb2], bp[2 * kb2],     oacc[1][0]);
      oacc[0][1] = mfma16(vavr[kb2],     bp[2 * kb2 + 1], oacc[0][1]);
      oacc[1][1] = mfma16(vavr[2 + kb2], bp[2 * kb2 + 1], oacc[1][1]);
      accL[0] = mfma16(ones, bp[2 * kb2],     accL[0]);
      accL[1] = mfma16(ones, bp[2 * kb2 + 1], accL[1]);
    }
  }

  // ---- epilogue: store partial O (f32) and partial l ----
  #pragma unroll
  for (int ct = 0; ct < 2; ++ct) {
    const int qg = qblk * 128 + wv * 32 + ct * 16 + l16;
    float* obase = Opart + ((size_t)(half * 16 + bh) * NSEQ + qg) * HD;
    #pragma unroll
    for (int dt = 0; dt < 2; ++dt) {
      float4 ov;
      ov.x = oacc[dt][ct][0]; ov.y = oacc[dt][ct][1];
      ov.z = oacc[dt][ct][2]; ov.w = oacc[dt][ct][3];
      *reinterpret_cast<float4*>(obase + dt * 16 + quad * 4) = ov;
    }
    if (quad == 0)
      Lpart[(size_t)(half * 16 + bh) * NSEQ + qg] = accL[ct][0];
  }
}

// ---------------- combine the two KV-halves: O=(O0+O1)/(l0+l1), write bf16 xa ----------------
__global__ __launch_bounds__(256) void fa_combine(const float* __restrict__ Opart,
                                                  const float* __restrict__ Lpart,
                                                  unsigned short* __restrict__ xa) {
  const int t  = blockIdx.x * 256 + threadIdx.x;   // 0..262143
  const int c8 = t & 3;                            // col group of 8
  const int n  = (t >> 2) & 4095;
  const int bh = t >> 14;
  const int b  = bh >> 3, h = bh & 7;

  const size_t o0 = ((size_t)bh * NSEQ + n) * HD + c8 * 8;
  const size_t o1 = o0 + (size_t)16 * NSEQ * HD;
  const float4 a0 = *reinterpret_cast<const float4*>(Opart + o0);
  const float4 a1 = *reinterpret_cast<const float4*>(Opart + o0 + 4);
  const float4 b0 = *reinterpret_cast<const float4*>(Opart + o1);
  const float4 b1 = *reinterpret_cast<const float4*>(Opart + o1 + 4);
  const float l0 = Lpart[(size_t)bh * NSEQ + n];
  const float l1 = Lpart[(size_t)(16 + bh) * NSEQ + n];
  const float rl = 1.f / (l0 + l1);

  uint4 ow;
  ow.x = pk_bf_rnd((a0.x + b0.x) * rl, (a0.y + b0.y) * rl);
  ow.y = pk_bf_rnd((a0.z + b0.z) * rl, (a0.w + b0.w) * rl);
  ow.z = pk_bf_rnd((a1.x + b1.x) * rl, (a1.y + b1.y) * rl);
  ow.w = pk_bf_rnd((a1.z + b1.z) * rl, (a1.w + b1.w) * rl);
  *reinterpret_cast<uint4*>(xa + ((size_t)b * NSEQ + n) * CCH + h * HD + c8 * 8) = ow;
}

extern "C" void kernel_launch(void* const* d_in, const int* in_sizes, int n_in,
                              void* d_out, int out_size, void* d_ws, size_t ws_size,
                              hipStream_t stream) {
  const float* x      = (const float*)d_in[0];
  const float* norm_w = (const float*)d_in[1];
  const float* norm_b = (const float*)d_in[2];
  const float* qkv_w  = (const float*)d_in[3];
  const float* qkv_b  = (const float*)d_in[4];
  const float* proj_w = (const float*)d_in[5];
  const float* proj_b = (const float*)d_in[6];
  const float* gamma  = (const float*)d_in[7];
  float* out = (float*)d_out;

  char* ws = (char*)d_ws;
  unsigned short* xn  = (unsigned short*)(ws);              // (B,N,C) bf16, 4 MiB
  unsigned short* qwb = (unsigned short*)(ws + 4194304);
  unsigned short* pwb = (unsigned short*)(ws + 4587520);
  unsigned short* q   = (unsigned short*)(ws + 4718592);    // (B,NH,N,HD), pre-scaled
  unsigned short* k   = (unsigned short*)(ws + 8912896);    // (B,NH,N,HD)
  unsigned short* vt  = (unsigned short*)(ws + 13107200);   // (B,NH,HD,N)
  unsigned short* xa  = (unsigned short*)(ws + 17301504);   // (B,N,C) bf16, 4 MiB
  float* Opart        = (float*)(ws + 21495808);            // [2][16][N][HD] f32, 16 MiB
  float* Lpart        = (float*)(ws + 38273024);            // [2][16][N] f32, 512 KiB

  hipLaunchKernelGGL(ln_cvt_kernel, dim3(512), dim3(256), 0, stream,
                     x, norm_w, norm_b, xn, qkv_w, proj_w, qwb, pwb);
  hipLaunchKernelGGL(qkv_gemm,  dim3(128, 12), dim3(256), 0, stream, xn, qwb, qkv_b, q, k, vt);
  hipLaunchKernelGGL(fa_kernel, dim3(1024), dim3(256), 0, stream, q, k, vt, Opart, Lpart);
  hipLaunchKernelGGL(fa_combine, dim3(1024), dim3(256), 0, stream, Opart, Lpart, xa);
  hipLaunchKernelGGL(proj_gemm, dim3(128, 8), dim3(256), 0, stream, xa, pwb, proj_b, gamma, x, out);
}